// Round 13
// baseline (1239.597 us; speedup 1.0000x reference)
//
#include <hip/hip_runtime.h>
#include <hip/hip_bf16.h>

// BiLSTM-CRF forward decode, f32 exact-path implementation.
// Phases:
//   P: one-time Whh transpose -> Wt[dir][k][j*4+gate]
//   A: embedding gather + input projection GEMM -> xq[dir][b][s][j*4+gate]
//      (128x128 tile, 8x8 per thread - correctness-verified in R11 run)
//   B: per-(dir,batch) persistent LSTM scan. 64 independent groups of 4
//      blocks; weights register-resident. Handshake: STAMPED 8-byte ATOMS
//      {h:f32, stamp:u32} - one relaxed agent load = detect + data.
//      LATENCY-BOUND FLOOR (~3.07us/step): three structural attacks
//      (barrier-free, dual-poll, dual-rec interleave) all regressed; do not
//      restructure this kernel without new evidence.
//   C: feats = concat(hf,hb) @ Wout^T + bout
//   D: Viterbi scan + backtrace -> int32 tags

#define S_LEN 256
#define BATCH 32
#define NTAG  24

typedef unsigned long long ull;

// ---------------------------------------------------------------- Phase P
// Wt[dir][k][j*4+g] = Whh_dir[g*256 + j][k]   (2 x 256 x 1024 floats)
__global__ __launch_bounds__(256) void k_prep(
    const float* __restrict__ WhhF, const float* __restrict__ WhhB,
    float* __restrict__ Wt) {
  int idx = blockIdx.x * 256 + threadIdx.x;   // 524288 total
  int dir = idx >> 18;
  int r = idx & 262143;
  int k = r >> 10;
  int jg = r & 1023;
  int j = jg >> 2, g = jg & 3;
  const float* W = dir ? WhhB : WhhF;
  Wt[idx] = W[(size_t)(g * 256 + j) * 256 + k];
}

// ---------------------------------------------------------------- Phase A
// 128 (s,b)-rows x 128 g-cols per block, 256 threads, 8x8 outputs/thread.
__global__ __launch_bounds__(256) void k_inproj(
    const int* __restrict__ sent, const float* __restrict__ embed,
    const float* __restrict__ WihF, const float* __restrict__ bihF, const float* __restrict__ bhhF,
    const float* __restrict__ WihB, const float* __restrict__ bihB, const float* __restrict__ bhhB,
    float* __restrict__ xq) {
  int tm = blockIdx.x;   // 0..63 : 128 (s,b)-rows each
  int tn = blockIdx.y;   // 0..7  : 128 g-cols each
  int dir = blockIdx.z;
  const float* Wih = dir ? WihB : WihF;
  const float* bih = dir ? bihB : bihF;
  const float* bhh = dir ? bhhB : bhhF;
  __shared__ float As[128 * 36];
  __shared__ float Bs[128 * 36];
  __shared__ int toks[128];
  int tid = threadIdx.x;
  if (tid < 128) {
    int r = tm * 128 + tid;
    int s = r >> 5, b = r & 31;
    toks[tid] = sent[b * S_LEN + s];
  }
  __syncthreads();
  int mt = tid & 15, nt = tid >> 4;
  float acc[8][8] = {};
  for (int k0 = 0; k0 < 256; k0 += 32) {
#pragma unroll
    for (int it = 0; it < 8; ++it) {
      int u = it * 256 + tid;
      if (u < 1024) {                 // A panel: 128 rows x 8 float4
        int row = u >> 3, lf = u & 7;
        *(float4*)&As[row * 36 + lf * 4] =
            *(const float4*)&embed[(size_t)toks[row] * 256 + k0 + lf * 4];
      } else {                        // B panel: 128 gate-rows x 8 float4
        int v2 = u - 1024;
        int row = v2 >> 3, lf = v2 & 7;
        *(float4*)&Bs[row * 36 + lf * 4] =
            *(const float4*)&Wih[(size_t)(tn * 128 + row) * 256 + k0 + lf * 4];
      }
    }
    __syncthreads();
#pragma unroll
    for (int kc = 0; kc < 8; ++kc) {
      float4 a[8], w[8];
#pragma unroll
      for (int i = 0; i < 8; ++i) a[i] = *(const float4*)&As[(mt + 16 * i) * 36 + kc * 4];
#pragma unroll
      for (int j = 0; j < 8; ++j) w[j] = *(const float4*)&Bs[(nt + 16 * j) * 36 + kc * 4];
#pragma unroll
      for (int i = 0; i < 8; ++i)
#pragma unroll
        for (int j = 0; j < 8; ++j)
          acc[i][j] += a[i].x * w[j].x + a[i].y * w[j].y + a[i].z * w[j].z + a[i].w * w[j].w;
    }
    __syncthreads();
  }
#pragma unroll
  for (int i = 0; i < 8; ++i) {
    int r = tm * 128 + mt + 16 * i;
    int s = r >> 5, b = r & 31;
#pragma unroll
    for (int j = 0; j < 8; ++j) {
      int gg = tn * 128 + nt + 16 * j;       // gate row 0..1023
      float v = acc[i][j] + bih[gg] + bhh[gg];
      // unit-interleaved layout: [dir][b][s][j*4 + gate]
      xq[(((size_t)(dir * 32 + b)) * 256 + s) * 1024 + (gg & 255) * 4 + (gg >> 8)] = v;
    }
  }
}

// ---------------------------------------------------------------- Phase B
// 256 blocks = 64 groups (dir,b) x 4 weight-slices q. Block (dir,b,q) owns
// units [q*64, q*64+64); weights in VGPRs/AGPRs for the whole scan.
// Handshake: hX2[par][dir][b][unit] holds an 8-byte atom {h, stamp}.
// Producer (wave0 lane l) stores {h, t+1} into buf[(t+1)&1] - no drain, no
// flag. Consumer lane (w,l) polls atom k=w*64+l of buf[t&1] until stamp==t;
// 8B-aligned accesses are single-copy atomic, so value+stamp arrive
// consistently. Depth-2 ping-pong WAR safety is transitive: a producer
// reaches its t+2 write only after consuming all members' t+1 atoms, which
// were published only after those members consumed buf@t.
// memset-0 per launch = {h=0, stamp=0} = the t=0 initial state.
__global__ __launch_bounds__(256, 1) void k_lstm(
    const float* __restrict__ Wt,            // [2][256][1024]
    const float* __restrict__ xq,            // [2][32][256][1024]
    ull* __restrict__ hX2,                   // [2 par][2 dir][32 b][256 unit]
    float* __restrict__ hsF) {               // [2 dir][32 b][256 s][256 j]
  int B = blockIdx.x;
  int q = (B >> 3) & 3;                    // weight slice
  int gid = (B & 7) | ((B >> 5) << 3);     // group id (members differ only in q)
  int dir = gid >> 5;
  int b = gid & 31;
  int tid = threadIdx.x;
  int w = tid >> 6;        // wave = k-slice index
  int l = tid & 63;        // lane
  int kbase = w * 64;
  int unit = q * 64 + l;   // unit owned by lane l (wave 0 epilogue role)

  __shared__ float red[4][64 * 8];   // [wave][lane*8 + gate], float4-aligned

  // one-time: weight slice into registers. wreg[kk] = Wt[dir][kbase+kk][unit*4..+3]
  float4 wreg[64];
  {
    const float* wp = Wt + ((size_t)dir * 256 + kbase) * 1024 + unit * 4;
#pragma unroll
    for (int kk = 0; kk < 64; ++kk)
      wreg[kk] = *(const float4*)(wp + (size_t)kk * 1024);
  }

  float c_st = 0.f;

#pragma unroll 1
  for (int t = 0; t < 256; ++t) {
    int s = dir ? (255 - t) : t;

    // wave0: prefetch xq (independent of sync -> hides under poll)
    float4 xv = {0.f, 0.f, 0.f, 0.f};
    if (w == 0)
      xv = *(const float4*)&xq[(((size_t)(dir * 32 + b)) * 256 + s) * 1024 + unit * 4];

    // poll own atom of buf[t&1] until stamp == t; payload rides along
    float hval;
    {
      const ull* hp =
          hX2 + ((((size_t)(t & 1) * 2 + dir) * 32 + b) * 256 + kbase + l);
      ull a;
      unsigned spins = 0;
      while (true) {
        a = __hip_atomic_load(hp, __ATOMIC_RELAXED, __HIP_MEMORY_SCOPE_AGENT);
        if (__all((unsigned)(a >> 32) == (unsigned)t)) break;
        if (++spins > (1u << 18)) break;   // safety: never hang the harness
      }
      hval = __uint_as_float((unsigned)a);
    }

    // GEMV slice: acc[g] += W[unit,g][k] * h[k], h broadcast via shfl
    float4 acc = {0.f, 0.f, 0.f, 0.f};
#pragma unroll
    for (int kk = 0; kk < 64; ++kk) {
      float hk = __shfl(hval, kk);
      acc.x += wreg[kk].x * hk;
      acc.y += wreg[kk].y * hk;
      acc.z += wreg[kk].z * hk;
      acc.w += wreg[kk].w * hk;
    }
    *(float4*)&red[w][l * 8] = acc;
    __syncthreads();   // the only barrier per step

    if (w == 0) {
      float4 r0 = *(const float4*)&red[0][l * 8];
      float4 r1 = *(const float4*)&red[1][l * 8];
      float4 r2 = *(const float4*)&red[2][l * 8];
      float4 r3 = *(const float4*)&red[3][l * 8];
      float xi = r0.x + r1.x + r2.x + r3.x + xv.x;
      float xf = r0.y + r1.y + r2.y + r3.y + xv.y;
      float xg = r0.z + r1.z + r2.z + r3.z + xv.z;
      float xo = r0.w + r1.w + r2.w + r3.w + xv.w;
      float si = 1.f / (1.f + expf(-xi));
      float sf = 1.f / (1.f + expf(-xf));
      float so = 1.f / (1.f + expf(-xo));
      float tg = tanhf(xg);
      float c = sf * c_st + si * tg;
      c_st = c;
      float h = so * tanhf(c);
      // publish stamped atom {h, t+1} into buf[(t+1)&1] - no drain needed
      ull atom =
          ((ull)(unsigned)(t + 1) << 32) |
          (ull)__float_as_uint(h);
      ull* hn =
          hX2 + ((((size_t)((t + 1) & 1) * 2 + dir) * 32 + b) * 256 + unit);
      __hip_atomic_store(hn, atom, __ATOMIC_RELAXED, __HIP_MEMORY_SCOPE_AGENT);
      // archive for k_feats - plain store, off the critical path
      hsF[(((size_t)(dir * 32 + b)) * 256 + s) * 256 + unit] = h;
    }
    // waves 1-3 proceed to next poll; WAR on red[] is gated by the stamps:
    // they cannot pass poll(t+1) until our wave0 (which already read red)
    // publishes its t+1 atoms.
  }
}

// ---------------------------------------------------------------- Phase C
__global__ __launch_bounds__(256) void k_feats(
    const float* __restrict__ hsF, const float* __restrict__ Wout,
    const float* __restrict__ bout, float* __restrict__ feats) {
  int s = blockIdx.x;
  int tid = threadIdx.x;
  __shared__ float Hl[32 * 260];
  __shared__ float Wl[24 * 260];
  float acc[3] = {};
  for (int dir = 0; dir < 2; ++dir) {
    __syncthreads();
    for (int u = tid; u < 8192; u += 256) {
      int b = u >> 8, j = u & 255;
      Hl[b * 260 + j] = hsF[(((size_t)(dir * 32 + b)) * 256 + s) * 256 + j];
    }
    for (int u = tid; u < 24 * 256; u += 256) {
      int t = u >> 8, j = u & 255;
      Wl[t * 260 + j] = Wout[t * 512 + dir * 256 + j];
    }
    __syncthreads();
    int b = tid & 31, th = tid >> 5;
    for (int jc = 0; jc < 64; ++jc) {
      float4 hv = *(const float4*)&Hl[b * 260 + jc * 4];
#pragma unroll
      for (int rep = 0; rep < 3; ++rep) {
        int t = rep * 8 + th;
        float4 wv = *(const float4*)&Wl[t * 260 + jc * 4];
        acc[rep] += hv.x * wv.x + hv.y * wv.y + hv.z * wv.z + hv.w * wv.w;
      }
    }
  }
  int b = tid & 31, th = tid >> 5;
#pragma unroll
  for (int rep = 0; rep < 3; ++rep) {
    int t = rep * 8 + th;
    feats[((size_t)s * 32 + b) * 24 + t] = acc[rep] + bout[t];
  }
}

// ---------------------------------------------------------------- Phase D
__global__ __launch_bounds__(64) void k_viterbi(
    const float* __restrict__ feats, const float* __restrict__ trans,
    const float* __restrict__ start_t, const float* __restrict__ stop_t,
    int* __restrict__ out) {
  int b = blockIdx.x;
  int j = threadIdx.x;
  bool act = j < NTAG;
  int j2 = act ? j : 0;
  __shared__ unsigned char idxL[255 * 24];
  __shared__ float sv[32];
  float tr[24];
#pragma unroll
  for (int i = 0; i < 24; ++i) tr[i] = trans[i * 24 + j2];
  float vj = feats[(size_t)b * 24 + j2] + start_t[j2];   // s=0: (0*32+b)*24
  if (!act) vj = -1e30f;
#pragma unroll 1
  for (int s = 1; s < 256; ++s) {
    float m = -1e30f;
    int arg = 0;
#pragma unroll
    for (int i = 0; i < 24; ++i) {
      float vi = __shfl(vj, i);
      float sc = vi + tr[i];
      if (sc > m) { m = sc; arg = i; }   // strict > keeps FIRST max (argmax semantics)
    }
    float fj = feats[((size_t)s * 32 + b) * 24 + j2];
    if (act) {
      idxL[(s - 1) * 24 + j] = (unsigned char)arg;
      vj = m + fj;
    }
  }
  if (act) sv[j] = vj + stop_t[j];
  __syncthreads();
  if (j == 0) {
    float m = sv[0];
    int tag = 0;
    for (int i = 1; i < 24; ++i)
      if (sv[i] > m) { m = sv[i]; tag = i; }
    out[b * 256 + 255] = tag;
    for (int s = 254; s >= 0; --s) {
      tag = idxL[s * 24 + tag];
      out[b * 256 + s] = tag;
    }
  }
}

// ---------------------------------------------------------------- host
extern "C" void kernel_launch(void* const* d_in, const int* in_sizes, int n_in,
                              void* d_out, int out_size, void* d_ws, size_t ws_size,
                              hipStream_t stream) {
  const int*   sent   = (const int*)  d_in[0];
  const float* embed  = (const float*)d_in[1];
  const float* WihF   = (const float*)d_in[2];
  const float* WhhF   = (const float*)d_in[3];
  const float* bihF   = (const float*)d_in[4];
  const float* bhhF   = (const float*)d_in[5];
  const float* WihB   = (const float*)d_in[6];
  const float* WhhB   = (const float*)d_in[7];
  const float* bihB   = (const float*)d_in[8];
  const float* bhhB   = (const float*)d_in[9];
  const float* Wout   = (const float*)d_in[10];
  const float* bout   = (const float*)d_in[11];
  const float* trans  = (const float*)d_in[12];
  const float* startt = (const float*)d_in[13];
  const float* stopt  = (const float*)d_in[14];
  int* out = (int*)d_out;

  char* ws = (char*)d_ws;
  size_t off = 0;
  float* xq = (float*)(ws + off);           off += (size_t)2 * 32 * 256 * 1024 * 4;  // 64 MB
  size_t off_sync = off;
  ull* hX2 = (ull*)(ws + off);              off += (size_t)2 * 2 * 32 * 256 * 8;     // 1 MB
  size_t sync_len = off - off_sync;
  float* hsF = (float*)(ws + off);          off += (size_t)2 * 32 * 256 * 256 * 4;   // 16 MB
  float* feats = (float*)(ws + off);        off += (size_t)256 * 32 * 24 * 4;        // 768 KB
  float* Wt = (float*)(ws + off);           off += (size_t)2 * 256 * 1024 * 4;       // 2 MB

  // zero the stamped-atom ping-pong ({h=0, stamp=0} == t=0 initial state);
  // stamps are consumed monotonically -> must re-zero every launch/replay
  hipMemsetAsync(ws + off_sync, 0, sync_len, stream);

  k_prep<<<2048, 256, 0, stream>>>(WhhF, WhhB, Wt);
  k_inproj<<<dim3(64, 8, 2), 256, 0, stream>>>(sent, embed, WihF, bihF, bhhF,
                                               WihB, bihB, bhhB, xq);
  k_lstm<<<256, 256, 0, stream>>>(Wt, xq, hX2, hsF);
  k_feats<<<256, 256, 0, stream>>>(hsF, Wout, bout, feats);
  k_viterbi<<<32, 64, 0, stream>>>(feats, trans, startt, stopt, out);
}

// Round 14
// 1064.923 us; speedup vs baseline: 1.1640x; 1.1640x over previous
//
#include <hip/hip_runtime.h>
#include <hip/hip_bf16.h>

// BiLSTM-CRF forward decode, f32 exact-path implementation.
// Phases:
//   P: one-time Whh transpose -> Wt[dir][k][j*4+gate]  (+ zeroes hX2:
//      replaces the hipMemsetAsync dispatch)
//   A: embedding gather + input projection GEMM -> xq[dir][b][s][j*4+gate]
//      64x64 tile, 4x4/thread (128x128 regressed: 4 vs 8 blocks/CU, R13).
//      Thread-tile roles chosen so xq stores are coalesced (16B/lane runs).
//   B: per-(dir,batch) persistent LSTM scan. 64 independent groups of 4
//      blocks; weights register-resident. Handshake: STAMPED 8-byte ATOMS
//      {h:f32, stamp:u32} - one relaxed agent load = detect + data.
//      LATENCY-BOUND FLOOR (~3.07us/step): three structural attacks
//      (barrier-free, dual-poll, dual-rec interleave) all regressed; do not
//      restructure this kernel without new evidence.
//   C: feats = concat(hf,hb) @ Wout^T + bout
//   D: Viterbi scan + backtrace -> int32 tags

#define S_LEN 256
#define BATCH 32
#define NTAG  24

typedef unsigned long long ull;

// ---------------------------------------------------------------- Phase P
// Wt[dir][k][j*4+g] = Whh_dir[g*256 + j][k]   (2 x 256 x 1024 floats)
// Also zeroes the 131072-entry hX2 stamped-atom buffer ({h=0,stamp=0} is
// the t=0 initial state; must be re-zeroed every launch/replay).
__global__ __launch_bounds__(256) void k_prep(
    const float* __restrict__ WhhF, const float* __restrict__ WhhB,
    float* __restrict__ Wt, ull* __restrict__ hX2) {
  int idx = blockIdx.x * 256 + threadIdx.x;   // 524288 total
  if (idx < 131072) hX2[idx] = 0ull;
  int dir = idx >> 18;
  int r = idx & 262143;
  int k = r >> 10;
  int jg = r & 1023;
  int j = jg >> 2, g = jg & 3;
  const float* W = dir ? WhhB : WhhF;
  Wt[idx] = W[(size_t)(g * 256 + j) * 256 + k];
}

// ---------------------------------------------------------------- Phase A
// 64 (s,b)-rows x 64 g-cols per block, 256 threads, 4x4 outputs/thread.
// mt = tid>>4 (row), nt = tid&15 (gate-col): consecutive lanes vary nt ->
// consecutive gg -> xq addresses stride 16B -> 256B contiguous runs per
// 16-lane group (the R12 layout stored at ~1MB lane strides).
__global__ __launch_bounds__(256) void k_inproj(
    const int* __restrict__ sent, const float* __restrict__ embed,
    const float* __restrict__ WihF, const float* __restrict__ bihF, const float* __restrict__ bhhF,
    const float* __restrict__ WihB, const float* __restrict__ bihB, const float* __restrict__ bhhB,
    float* __restrict__ xq) {
  int tm = blockIdx.x;   // 0..127 : 64 (s,b)-rows each
  int tn = blockIdx.y;   // 0..15  : 64 g-cols each
  int dir = blockIdx.z;
  const float* Wih = dir ? WihB : WihF;
  const float* bih = dir ? bihB : bihF;
  const float* bhh = dir ? bhhB : bhhF;
  __shared__ float As[64 * 36];
  __shared__ float Bs[64 * 36];
  __shared__ int toks[64];
  int tid = threadIdx.x;
  if (tid < 64) {
    int r = tm * 64 + tid;
    int s = r >> 5, b = r & 31;
    toks[tid] = sent[b * S_LEN + s];
  }
  __syncthreads();
  int mt = tid >> 4, nt = tid & 15;
  float acc[4][4] = {};
  for (int k0 = 0; k0 < 256; k0 += 32) {
    for (int it = 0; it < 2; ++it) {
      int u = it * 256 + tid;
      int row = u >> 3, lf = u & 7;
      float4 av = *(const float4*)&embed[(size_t)toks[row] * 256 + k0 + lf * 4];
      *(float4*)&As[row * 36 + lf * 4] = av;
      int grow = tn * 64 + row;
      float4 wv = *(const float4*)&Wih[(size_t)grow * 256 + k0 + lf * 4];
      *(float4*)&Bs[row * 36 + lf * 4] = wv;
    }
    __syncthreads();
#pragma unroll
    for (int kc = 0; kc < 8; ++kc) {
      float4 a[4], w[4];
#pragma unroll
      for (int i = 0; i < 4; ++i) a[i] = *(const float4*)&As[(mt + 16 * i) * 36 + kc * 4];
#pragma unroll
      for (int j = 0; j < 4; ++j) w[j] = *(const float4*)&Bs[(nt + 16 * j) * 36 + kc * 4];
#pragma unroll
      for (int i = 0; i < 4; ++i)
#pragma unroll
        for (int j = 0; j < 4; ++j)
          acc[i][j] += a[i].x * w[j].x + a[i].y * w[j].y + a[i].z * w[j].z + a[i].w * w[j].w;
    }
    __syncthreads();
  }
#pragma unroll
  for (int i = 0; i < 4; ++i) {
    int r = tm * 64 + mt + 16 * i;
    int s = r >> 5, b = r & 31;
#pragma unroll
    for (int j = 0; j < 4; ++j) {
      int gg = tn * 64 + nt + 16 * j;       // gate row 0..1023
      float v = acc[i][j] + bih[gg] + bhh[gg];
      // unit-interleaved layout: [dir][b][s][j*4 + gate]
      xq[(((size_t)(dir * 32 + b)) * 256 + s) * 1024 + (gg & 255) * 4 + (gg >> 8)] = v;
    }
  }
}

// ---------------------------------------------------------------- Phase B
// 256 blocks = 64 groups (dir,b) x 4 weight-slices q. Block (dir,b,q) owns
// units [q*64, q*64+64); weights in VGPRs/AGPRs for the whole scan.
// Handshake: hX2[par][dir][b][unit] holds an 8-byte atom {h, stamp}.
// Producer (wave0 lane l) stores {h, t+1} into buf[(t+1)&1] - no drain, no
// flag. Consumer lane (w,l) polls atom k=w*64+l of buf[t&1] until stamp==t;
// 8B-aligned accesses are single-copy atomic, so value+stamp arrive
// consistently. Depth-2 ping-pong WAR safety is transitive: a producer
// reaches its t+2 write only after consuming all members' t+1 atoms, which
// were published only after those members consumed buf@t.
__global__ __launch_bounds__(256, 1) void k_lstm(
    const float* __restrict__ Wt,            // [2][256][1024]
    const float* __restrict__ xq,            // [2][32][256][1024]
    ull* __restrict__ hX2,                   // [2 par][2 dir][32 b][256 unit]
    float* __restrict__ hsF) {               // [2 dir][32 b][256 s][256 j]
  int B = blockIdx.x;
  int q = (B >> 3) & 3;                    // weight slice
  int gid = (B & 7) | ((B >> 5) << 3);     // group id (members differ only in q)
  int dir = gid >> 5;
  int b = gid & 31;
  int tid = threadIdx.x;
  int w = tid >> 6;        // wave = k-slice index
  int l = tid & 63;        // lane
  int kbase = w * 64;
  int unit = q * 64 + l;   // unit owned by lane l (wave 0 epilogue role)

  __shared__ float red[4][64 * 8];   // [wave][lane*8 + gate], float4-aligned

  // one-time: weight slice into registers. wreg[kk] = Wt[dir][kbase+kk][unit*4..+3]
  float4 wreg[64];
  {
    const float* wp = Wt + ((size_t)dir * 256 + kbase) * 1024 + unit * 4;
#pragma unroll
    for (int kk = 0; kk < 64; ++kk)
      wreg[kk] = *(const float4*)(wp + (size_t)kk * 1024);
  }

  float c_st = 0.f;

#pragma unroll 1
  for (int t = 0; t < 256; ++t) {
    int s = dir ? (255 - t) : t;

    // wave0: prefetch xq (independent of sync -> hides under poll)
    float4 xv = {0.f, 0.f, 0.f, 0.f};
    if (w == 0)
      xv = *(const float4*)&xq[(((size_t)(dir * 32 + b)) * 256 + s) * 1024 + unit * 4];

    // poll own atom of buf[t&1] until stamp == t; payload rides along
    float hval;
    {
      const ull* hp =
          hX2 + ((((size_t)(t & 1) * 2 + dir) * 32 + b) * 256 + kbase + l);
      ull a;
      unsigned spins = 0;
      while (true) {
        a = __hip_atomic_load(hp, __ATOMIC_RELAXED, __HIP_MEMORY_SCOPE_AGENT);
        if (__all((unsigned)(a >> 32) == (unsigned)t)) break;
        if (++spins > (1u << 18)) break;   // safety: never hang the harness
      }
      hval = __uint_as_float((unsigned)a);
    }

    // GEMV slice: acc[g] += W[unit,g][k] * h[k], h broadcast via shfl
    float4 acc = {0.f, 0.f, 0.f, 0.f};
#pragma unroll
    for (int kk = 0; kk < 64; ++kk) {
      float hk = __shfl(hval, kk);
      acc.x += wreg[kk].x * hk;
      acc.y += wreg[kk].y * hk;
      acc.z += wreg[kk].z * hk;
      acc.w += wreg[kk].w * hk;
    }
    *(float4*)&red[w][l * 8] = acc;
    __syncthreads();   // the only barrier per step

    if (w == 0) {
      float4 r0 = *(const float4*)&red[0][l * 8];
      float4 r1 = *(const float4*)&red[1][l * 8];
      float4 r2 = *(const float4*)&red[2][l * 8];
      float4 r3 = *(const float4*)&red[3][l * 8];
      float xi = r0.x + r1.x + r2.x + r3.x + xv.x;
      float xf = r0.y + r1.y + r2.y + r3.y + xv.y;
      float xg = r0.z + r1.z + r2.z + r3.z + xv.z;
      float xo = r0.w + r1.w + r2.w + r3.w + xv.w;
      float si = 1.f / (1.f + expf(-xi));
      float sf = 1.f / (1.f + expf(-xf));
      float so = 1.f / (1.f + expf(-xo));
      float tg = tanhf(xg);
      float c = sf * c_st + si * tg;
      c_st = c;
      float h = so * tanhf(c);
      // publish stamped atom {h, t+1} into buf[(t+1)&1] - no drain needed
      ull atom =
          ((ull)(unsigned)(t + 1) << 32) |
          (ull)__float_as_uint(h);
      ull* hn =
          hX2 + ((((size_t)((t + 1) & 1) * 2 + dir) * 32 + b) * 256 + unit);
      __hip_atomic_store(hn, atom, __ATOMIC_RELAXED, __HIP_MEMORY_SCOPE_AGENT);
      // archive for k_feats - plain store, off the critical path
      hsF[(((size_t)(dir * 32 + b)) * 256 + s) * 256 + unit] = h;
    }
    // waves 1-3 proceed to next poll; WAR on red[] is gated by the stamps:
    // they cannot pass poll(t+1) until our wave0 (which already read red)
    // publishes its t+1 atoms.
  }
}

// ---------------------------------------------------------------- Phase C
__global__ __launch_bounds__(256) void k_feats(
    const float* __restrict__ hsF, const float* __restrict__ Wout,
    const float* __restrict__ bout, float* __restrict__ feats) {
  int s = blockIdx.x;
  int tid = threadIdx.x;
  __shared__ float Hl[32 * 260];
  __shared__ float Wl[24 * 260];
  float acc[3] = {};
  for (int dir = 0; dir < 2; ++dir) {
    __syncthreads();
    for (int u = tid; u < 8192; u += 256) {
      int b = u >> 8, j = u & 255;
      Hl[b * 260 + j] = hsF[(((size_t)(dir * 32 + b)) * 256 + s) * 256 + j];
    }
    for (int u = tid; u < 24 * 256; u += 256) {
      int t = u >> 8, j = u & 255;
      Wl[t * 260 + j] = Wout[t * 512 + dir * 256 + j];
    }
    __syncthreads();
    int b = tid & 31, th = tid >> 5;
    for (int jc = 0; jc < 64; ++jc) {
      float4 hv = *(const float4*)&Hl[b * 260 + jc * 4];
#pragma unroll
      for (int rep = 0; rep < 3; ++rep) {
        int t = rep * 8 + th;
        float4 wv = *(const float4*)&Wl[t * 260 + jc * 4];
        acc[rep] += hv.x * wv.x + hv.y * wv.y + hv.z * wv.z + hv.w * wv.w;
      }
    }
  }
  int b = tid & 31, th = tid >> 5;
#pragma unroll
  for (int rep = 0; rep < 3; ++rep) {
    int t = rep * 8 + th;
    feats[((size_t)s * 32 + b) * 24 + t] = acc[rep] + bout[t];
  }
}

// ---------------------------------------------------------------- Phase D
__global__ __launch_bounds__(64) void k_viterbi(
    const float* __restrict__ feats, const float* __restrict__ trans,
    const float* __restrict__ start_t, const float* __restrict__ stop_t,
    int* __restrict__ out) {
  int b = blockIdx.x;
  int j = threadIdx.x;
  bool act = j < NTAG;
  int j2 = act ? j : 0;
  __shared__ unsigned char idxL[255 * 24];
  __shared__ float sv[32];
  float tr[24];
#pragma unroll
  for (int i = 0; i < 24; ++i) tr[i] = trans[i * 24 + j2];
  float vj = feats[(size_t)b * 24 + j2] + start_t[j2];   // s=0: (0*32+b)*24
  if (!act) vj = -1e30f;
#pragma unroll 1
  for (int s = 1; s < 256; ++s) {
    float m = -1e30f;
    int arg = 0;
#pragma unroll
    for (int i = 0; i < 24; ++i) {
      float vi = __shfl(vj, i);
      float sc = vi + tr[i];
      if (sc > m) { m = sc; arg = i; }   // strict > keeps FIRST max (argmax semantics)
    }
    float fj = feats[((size_t)s * 32 + b) * 24 + j2];
    if (act) {
      idxL[(s - 1) * 24 + j] = (unsigned char)arg;
      vj = m + fj;
    }
  }
  if (act) sv[j] = vj + stop_t[j];
  __syncthreads();
  if (j == 0) {
    float m = sv[0];
    int tag = 0;
    for (int i = 1; i < 24; ++i)
      if (sv[i] > m) { m = sv[i]; tag = i; }
    out[b * 256 + 255] = tag;
    for (int s = 254; s >= 0; --s) {
      tag = idxL[s * 24 + tag];
      out[b * 256 + s] = tag;
    }
  }
}

// ---------------------------------------------------------------- host
extern "C" void kernel_launch(void* const* d_in, const int* in_sizes, int n_in,
                              void* d_out, int out_size, void* d_ws, size_t ws_size,
                              hipStream_t stream) {
  const int*   sent   = (const int*)  d_in[0];
  const float* embed  = (const float*)d_in[1];
  const float* WihF   = (const float*)d_in[2];
  const float* WhhF   = (const float*)d_in[3];
  const float* bihF   = (const float*)d_in[4];
  const float* bhhF   = (const float*)d_in[5];
  const float* WihB   = (const float*)d_in[6];
  const float* WhhB   = (const float*)d_in[7];
  const float* bihB   = (const float*)d_in[8];
  const float* bhhB   = (const float*)d_in[9];
  const float* Wout   = (const float*)d_in[10];
  const float* bout   = (const float*)d_in[11];
  const float* trans  = (const float*)d_in[12];
  const float* startt = (const float*)d_in[13];
  const float* stopt  = (const float*)d_in[14];
  int* out = (int*)d_out;

  char* ws = (char*)d_ws;
  size_t off = 0;
  float* xq = (float*)(ws + off);           off += (size_t)2 * 32 * 256 * 1024 * 4;  // 64 MB
  ull* hX2 = (ull*)(ws + off);              off += (size_t)2 * 2 * 32 * 256 * 8;     // 1 MB
  float* hsF = (float*)(ws + off);          off += (size_t)2 * 32 * 256 * 256 * 4;   // 16 MB
  float* feats = (float*)(ws + off);        off += (size_t)256 * 32 * 24 * 4;        // 768 KB
  float* Wt = (float*)(ws + off);           off += (size_t)2 * 256 * 1024 * 4;       // 2 MB

  // hX2 zeroing (the t=0 initial state) is folded into k_prep.
  k_prep<<<2048, 256, 0, stream>>>(WhhF, WhhB, Wt, hX2);
  k_inproj<<<dim3(128, 16, 2), 256, 0, stream>>>(sent, embed, WihF, bihF, bhhF,
                                                 WihB, bihB, bhhB, xq);
  k_lstm<<<256, 256, 0, stream>>>(Wt, xq, hX2, hsF);
  k_feats<<<256, 256, 0, stream>>>(hsF, Wout, bout, feats);
  k_viterbi<<<32, 64, 0, stream>>>(feats, trans, startt, stopt, out);
}